// Round 2
// 360.086 us; speedup vs baseline: 1.0235x; 1.0235x over previous
//
#include <hip/hip_runtime.h>
#include <hip/hip_fp16.h>
#include <cstdint>

// B=256, H=128, N=1000.
// logits[b,n] = sum_h v[h] * tanh( sum_{k<384} W[h,k]*X[b,k,n] + cterm[b,h] )
// out[b,n]    = softmax_n(logits[b,:])
// X = concat(adj, static, dyn); cterm = W[:,384:512] @ dec[b].
// Round 5 (= Round 4 resubmit after infra failure):
//   fp16 single MFMA (halves MFMA + pack VALU vs bf16 hi/lo, better absmax);
//   W staged in two K=192 passes -> LDS 52.2 KB -> 3 blocks/CU (24 waves, +50% TLP).

#define BB 256
#define HH 128
#define NN 1000
#define K3 384
#define KH 192                    // k columns per staging pass
#define WROW 400                  // LDS bytes per W row-half: 192*2 + 16 pad (16B aligned)
#define WLDS (HH * WROW)          // 51200
#define CT_OFF WLDS               // cterm row (128 f32)
#define VV_OFF (WLDS + 512)       // v vector (128 f32)
#define SMEM_ATTN (WLDS + 1024)   // 52224 B -> 3 blocks/CU (156.7 KB of 160)

typedef __attribute__((ext_vector_type(8))) _Float16 half8;
typedef __attribute__((ext_vector_type(4))) float f32x4;

__device__ __forceinline__ uint32_t pk_f16(float a, float b) {
    auto h = __builtin_amdgcn_cvt_pkrtz(a, b);   // v_cvt_pkrtz_f16_f32, 1 VALU
    return __builtin_bit_cast(uint32_t, h);
}
__device__ __forceinline__ float fast_tanh(float x) {
    float e = __expf(2.0f * x);
    return 1.0f - 2.0f * __builtin_amdgcn_rcpf(e + 1.0f);
}

// ---------------- prep: W -> fp16 + cterm mini-GEMM ----------------
__global__ void prep_kernel(const float* __restrict__ W, const float* __restrict__ dec,
                            uint16_t* __restrict__ Whf, float* __restrict__ cterm) {
    extern __shared__ float ls[];
    const int tid = threadIdx.x;
    if (blockIdx.x < 48) {
        // W[:, :384] -> fp16 (rne) ; 12288 float4 chunks, coalesced
        int idx4 = blockIdx.x * 256 + tid;
        int h = idx4 / 96, k4 = idx4 - h * 96;
        float4 w = *(const float4*)(W + h * 512 + k4 * 4);
        union { __half hx[4]; uint2 u; } o;
        o.hx[0] = __float2half_rn(w.x);
        o.hx[1] = __float2half_rn(w.y);
        o.hx[2] = __float2half_rn(w.z);
        o.hx[3] = __float2half_rn(w.w);
        *(uint2*)(Whf + h * K3 + k4 * 4) = o.u;
    } else {
        // cterm[b,h] = sum_k W[h,384+k]*dec[b,k]; 8 b per block, W4+dec in LDS (fp32 exact)
        float* w4 = ls;              // 128 x 129 (padded, conflict-free)
        float* dl = ls + 128 * 129;  // 8 x 128
        const int bb = (blockIdx.x - 48) * 8;
#pragma unroll
        for (int i = 0; i < 16; ++i) {
            int chunk = tid + i * 256;
            int h = chunk >> 5, kq = chunk & 31;
            float4 v = *(const float4*)(W + h * 512 + 384 + kq * 4);
            float* d = w4 + h * 129 + kq * 4;
            d[0] = v.x; d[1] = v.y; d[2] = v.z; d[3] = v.w;
        }
        {
            float4 dv = *(const float4*)(dec + bb * HH + tid * 4);
            float* d = dl + tid * 4;
            d[0] = dv.x; d[1] = dv.y; d[2] = dv.z; d[3] = dv.w;
        }
        __syncthreads();
#pragma unroll
        for (int r = 0; r < 4; ++r) {
            int o = tid + r * 256;
            int h = o & 127, bl_ = o >> 7;
            const float* wr = w4 + h * 129;
            const float* dr = dl + bl_ * 128;
            float s = 0.f;
#pragma unroll 8
            for (int k = 0; k < 128; ++k) s += wr[k] * dr[k];
            cterm[(bb + bl_) * HH + h] = s;
        }
    }
}

// ---------------- main: GEMM + tanh + v-dot -> logits ----------------
// 512 threads = 8 waves, each wave owns 16 n-columns; block tile = 128 n.
// grid = 256 b * 8 tiles. K processed in 2 passes of 192 with W restaged between.
__launch_bounds__(512, 6)
__global__ void attn_main(const float* __restrict__ adj, const float* __restrict__ sta,
                          const float* __restrict__ dyn,
                          const uint16_t* __restrict__ Whf,
                          const float* __restrict__ cterm, const float* __restrict__ vvec,
                          float* __restrict__ logits) {
    extern __shared__ char smem[];
    const int tid = threadIdx.x;
    const int b = blockIdx.x >> 3;
    const int tile = blockIdx.x & 7;

    const int wave = tid >> 6, lane = tid & 63;
    const int c = lane & 15, q = lane >> 4;
    const int n = tile * 128 + wave * 16 + c;
    const int ncl = (n < NN) ? n : NN - 1;
    const long bbase = (long)b * HH * NN;
    const float* A0 = adj + bbase;
    const float* A1 = sta + bbase;
    const float* A2 = dyn + bbase;

    f32x4 acc[8];
#pragma unroll
    for (int m = 0; m < 8; ++m) acc[m] = (f32x4){0.f, 0.f, 0.f, 0.f};

    union bu { uint32_t u[4]; half8 h; };
    bu bcur;

    // issue k-chunk 0 X loads first so they overlap W staging
    {
        const float* px = A0 + (8 * q) * NN + ncl;
        float x0[8];
#pragma unroll
        for (int j = 0; j < 8; ++j) x0[j] = px[j * NN];
#pragma unroll
        for (int j = 0; j < 4; ++j) bcur.u[j] = pk_f16(x0[2 * j], x0[2 * j + 1]);
    }

#pragma unroll
    for (int pp = 0; pp < 2; ++pp) {
        if (pp) __syncthreads();   // all waves done reading previous W half
        // stage W half pp: 128 rows x 384 B = 3072 x 16B chunks, 6 per thread
#pragma unroll
        for (int i = 0; i < 6; ++i) {
            int ch = tid + i * 512;
            int hr = ch / 24, j = ch - hr * 24;
            *(uint4*)(smem + hr * WROW + j * 16) =
                *(const uint4*)(Whf + hr * K3 + pp * KH + j * 8);
        }
        if (pp == 0) {
            if (tid < 32) {
                ((float4*)(smem + CT_OFF))[tid] = ((const float4*)(cterm + b * HH))[tid];
            } else if (tid < 64) {
                ((float4*)(smem + VV_OFF))[tid - 32] = ((const float4*)vvec)[tid - 32];
            }
        }
        __syncthreads();

#pragma unroll
        for (int it = 0; it < 6; ++it) {
            const int kk = pp * 6 + it;
            // prefetch next chunk's X while this chunk's MFMAs run
            float xf[8];
            if (kk + 1 < 12) {
                const int t2 = (kk + 1) >> 2, cc2 = (kk + 1) & 3;
                const float* base2 = (t2 == 0) ? A0 : ((t2 == 1) ? A1 : A2);
                const float* px = base2 + (cc2 * 32 + 8 * q) * NN + ncl;
#pragma unroll
                for (int j = 0; j < 8; ++j) xf[j] = px[j * NN];
            }
            const int rowoff = it * 64 + q * 16;
#pragma unroll
            for (int m = 0; m < 8; ++m) {
                const half8 av = *(const half8*)(smem + (m * 16 + c) * WROW + rowoff);
                acc[m] = __builtin_amdgcn_mfma_f32_16x16x32_f16(av, bcur.h, acc[m], 0, 0, 0);
            }
            if (kk + 1 < 12) {
#pragma unroll
                for (int j = 0; j < 4; ++j) bcur.u[j] = pk_f16(xf[2 * j], xf[2 * j + 1]);
            }
        }
    }

    // epilogue: C layout col=lane&15, row=q*4+r ; h = m*16 + q*4 + r
    const float* ct = (const float*)(smem + CT_OFF);
    const float* vv = (const float*)(smem + VV_OFF);
    float s = 0.0f;
#pragma unroll
    for (int m = 0; m < 8; ++m) {
#pragma unroll
        for (int r = 0; r < 4; ++r) {
            const int h = m * 16 + q * 4 + r;
            s += vv[h] * fast_tanh(acc[m][r] + ct[h]);
        }
    }
    s += __shfl_xor(s, 16, 64);
    s += __shfl_xor(s, 32, 64);
    if (lane < 16 && n < NN) logits[b * NN + n] = s;
}

// ---------------- softmax over n, in place on d_out ----------------
__global__ void softmax_kernel(float* __restrict__ out) {
    const int b = blockIdx.x;
    const int tid = threadIdx.x;
    float* row = out + b * NN;

    float vals[4];
#pragma unroll
    for (int i = 0; i < 4; ++i) {
        int j = tid + i * 256;
        vals[i] = (j < NN) ? row[j] : -1e30f;
    }
    float mx = fmaxf(fmaxf(vals[0], vals[1]), fmaxf(vals[2], vals[3]));
#pragma unroll
    for (int off = 1; off < 64; off <<= 1) mx = fmaxf(mx, __shfl_xor(mx, off, 64));
    __shared__ float smax[4];
    if ((tid & 63) == 0) smax[tid >> 6] = mx;
    __syncthreads();
    mx = fmaxf(fmaxf(smax[0], smax[1]), fmaxf(smax[2], smax[3]));

    float e[4];
    float s = 0.0f;
#pragma unroll
    for (int i = 0; i < 4; ++i) {
        int j = tid + i * 256;
        e[i] = (j < NN) ? __expf(vals[i] - mx) : 0.0f;
        s += e[i];
    }
#pragma unroll
    for (int off = 1; off < 64; off <<= 1) s += __shfl_xor(s, off, 64);
    __shared__ float ssum[4];
    if ((tid & 63) == 0) ssum[tid >> 6] = s;
    __syncthreads();
    s = ssum[0] + ssum[1] + ssum[2] + ssum[3];
    float inv = 1.0f / s;
#pragma unroll
    for (int i = 0; i < 4; ++i) {
        int j = tid + i * 256;
        if (j < NN) row[j] = e[i] * inv;
    }
}

extern "C" void kernel_launch(void* const* d_in, const int* in_sizes, int n_in,
                              void* d_out, int out_size, void* d_ws, size_t ws_size,
                              hipStream_t stream) {
    const float* adj = (const float*)d_in[0];
    const float* sta = (const float*)d_in[1];
    const float* dyn = (const float*)d_in[2];
    const float* dec = (const float*)d_in[3];
    const float* v   = (const float*)d_in[4];
    const float* W   = (const float*)d_in[5];

    uint16_t* Whf = (uint16_t*)d_ws;                 // 128*384*2 = 98304 B
    float* cterm  = (float*)(Whf + HH * K3);         // 256*128*4 = 131072 B
    float* logits = (float*)d_out;

    prep_kernel<<<80, 256, (128 * 129 + 1024) * 4, stream>>>(W, dec, Whf, cterm);
    attn_main<<<BB * 8, 512, SMEM_ATTN, stream>>>(adj, sta, dyn, Whf, cterm, v, logits);
    softmax_kernel<<<BB, 256, 0, stream>>>(logits);
}